// Round 3
// baseline (696.630 us; speedup 1.0000x reference)
//
#include <hip/hip_runtime.h>
#include <cstddef>
#include <cstdint>

#define Bn 256
#define Hd 128
#define Nd 2048
#define K3 384     // W row stride (3H)
#define NT 32      // n-tile of score_kernel

typedef _Float16 half8 __attribute__((ext_vector_type(8)));
typedef float    float4v __attribute__((ext_vector_type(4)));
typedef unsigned int u32;

__device__ __forceinline__ float fast_tanh(float x) {
    // tanh(x) = 1 - 2/(exp(2x)+1); saturates correctly at +/-inf
    return 1.0f - __fdividef(2.0f, __expf(2.0f * x) + 1.0f);
}

// async global->LDS DMA, 16B per lane. LDS dest must be wave-uniform base;
// HW adds lane*16. Casts via uintptr (CK-style): AS(3) ptr is the low 32
// bits of the flat shared address (aperture is 4GB-aligned).
__device__ __forceinline__ void dma16(const float* g, const void* l) {
    __builtin_amdgcn_global_load_lds(
        (const __attribute__((address_space(1))) u32*)(uintptr_t)g,
        (__attribute__((address_space(3))) u32*)(u32)(uintptr_t)l,
        16, 0, 0);
}

// ---------------------------------------------------------------------------
// prep 1: Wf[h][k] = fp16(W[h][k]) for k<256  (static+dynamic columns)
__global__ void prep_w16(const float* __restrict__ W, _Float16* __restrict__ Wf) {
    int idx = blockIdx.x * 256 + threadIdx.x;   // 0..32767
    int h = idx >> 8, k = idx & 255;
    Wf[idx] = (_Float16)W[h * K3 + k];
}

// prep 2: c[b][h] = sum_k W[h][256+k] * dec[b][k]  (decoder term, fp32 exact)
__global__ void prep_c(const float* __restrict__ W, const float* __restrict__ dec,
                       float* __restrict__ cb) {
    __shared__ float dl[Hd];
    int b = blockIdx.x;
    int h = threadIdx.x;       // 128 threads
    dl[h] = dec[b * Hd + h];
    __syncthreads();
    float acc = 0.f;
    #pragma unroll 8
    for (int k = 0; k < Hd; ++k)
        acc = fmaf(W[h * K3 + 256 + k], dl[k], acc);
    cb[b * Hd + h] = acc;
}

// ---------------------------------------------------------------------------
// Main: block = (b, 32-n tile), 512 threads = 8 waves, 3 blocks/CU
// (LDS 48.5 KB; __launch_bounds__(512,6) -> VGPR cap 85, 24 waves/CU).
//
// R2 post-mortem: VGPR=28 proved the compiler serializes register-staged
// loads (issue-wait-convert per load => ~8 serial HBM latencies/wave,
// in-flight ~3KB/CU vs 9.2KB needed). Fix: fire-and-forget DMA staging.
//
// Phase 1 (DMA): wave w covers logical k-rows [32w,32w+32) (w<4 static,
// w>=4 dynamic): 4 x global_load_lds(16B) -> xraw[k][n] f32 linear. All 32
// 1KB-instrs of the block issue with no register dependency; one vmcnt(0)
// at the barrier. In-flight ~= 24 waves x 4KB per CU => HBM-saturating.
// Phase 2 (cvt): thread t: n = t&31, kc in {t>>5, t>>5+16}; 8 ds_read_b32
// (bank = n&31: 2-way = free) -> cvt -> 1 swizzled half8 write into
// xl[n][k] f16, phys 16B-chunk = kc ^ (n&7).
// Phase 3 (MFMA): wave w -> (mh=w&3 -> h0=32mh, nh=w>>2 -> rows 16nh..):
// acc 2x1, 8 kt x (1 ds_read_b128 + 2 MFMA), Wf A-stream distance-1
// prefetch (L2-hot). Same fragment/swizzle algebra as validated R1/R2.
__global__ __launch_bounds__(512, 6)
void score_kernel(const float* __restrict__ shp, const float* __restrict__ dhp,
                  const _Float16* __restrict__ Wf, const float* __restrict__ cbp,
                  const float* __restrict__ v, float* __restrict__ out) {
    __shared__ __align__(16) float    xraw[256 * NT];   // [k][n] f32, 32 KB, linear
    __shared__ __align__(16) _Float16 xl[NT * 256];     // [n][k] f16, 16 KB, swizzled
    __shared__ float red[4 * NT];                       // 512 B

    const int tid  = threadIdx.x;
    const int w    = __builtin_amdgcn_readfirstlane(tid >> 6);  // wave id (SGPR)
    const int lane = tid & 63;
    const int qd   = lane >> 4;       // quad 0..3
    const int ln   = lane & 15;
    const int b    = blockIdx.y;
    const int n0   = blockIdx.x * NT;

    // ---- phase 1: DMA stage, 4 fire-and-forget 1KB instrs per wave.
    // instr t: lane i -> global x[kr + 8t + (i>>3)][n0 + 4(i&7)..+3],
    // LDS linear row (32w+8t+(i>>3)), byte (i&7)*16  (dest = base + i*16).
    {
        const float* arr = (w < 4) ? shp : dhp;
        const int kr = (w < 4) ? 32 * w : 32 * w - 128;   // row within arr
        const float* gb = arr + (size_t)b * (Hd * (size_t)Nd) + (size_t)kr * Nd
                        + (size_t)(lane >> 3) * Nd + n0 + 4 * (lane & 7);
        #pragma unroll
        for (int t = 0; t < 4; ++t)
            dma16(gb + (size_t)(8 * t) * Nd,
                  (const char*)xraw + (32 * w + 8 * t) * (NT * 4));
    }
    __syncthreads();   // emits s_waitcnt vmcnt(0) before s_barrier: DMA drained

    // ---- phase 2: cvt raw [k][n] f32 -> xl [n][k] f16 swizzled
    {
        const int n   = tid & 31;
        const int s   = n & 7;
        const int kc0 = tid >> 5;          // 0..15
        #pragma unroll
        for (int u = 0; u < 2; ++u) {
            const int kc = kc0 + 16 * u;   // 16B k-chunk 0..31
            half8 e;
            #pragma unroll
            for (int j = 0; j < 8; ++j)
                e[j] = (_Float16)xraw[(kc * 8 + j) * NT + n];
            *reinterpret_cast<half8*>(&xl[n * 256 + ((kc ^ s) << 3)]) = e;
        }
    }
    __syncthreads();

    // ---- phase 3: MFMA. A[m=ln][k=qd*8+j]; B[k=qd*8+j][n=ln].
    const int mh  = w & 3;            // h-tile group: h0 = 32*mh
    const int nh  = w >> 2;           // n-half: rows 16*nh ..
    const int h0  = mh * 32;
    const int row = nh * 16 + ln;     // 0..31
    const int sw  = row & 7;

    float4v acc0 = *reinterpret_cast<const float4v*>(cbp + b * Hd + h0 + qd * 4);
    float4v acc1 = *reinterpret_cast<const float4v*>(cbp + b * Hd + h0 + 16 + qd * 4);

    const _Float16* wp0 = Wf + ((h0 + ln) << 8) + qd * 8;
    const _Float16* wp1 = Wf + ((h0 + 16 + ln) << 8) + qd * 8;
    half8 a0 = *reinterpret_cast<const half8*>(wp0);
    half8 a1 = *reinterpret_cast<const half8*>(wp1);
    #pragma unroll
    for (int kt = 0; kt < 8; ++kt) {
        half8 a0n, a1n;
        if (kt < 7) {
            a0n = *reinterpret_cast<const half8*>(wp0 + (kt + 1) * 32);
            a1n = *reinterpret_cast<const half8*>(wp1 + (kt + 1) * 32);
        }
        const int ck = kt * 4 + qd;
        half8 Bf = *reinterpret_cast<const half8*>(&xl[row * 256 + ((ck ^ sw) << 3)]);
        acc0 = __builtin_amdgcn_mfma_f32_16x16x32_f16(a0, Bf, acc0, 0, 0, 0);
        acc1 = __builtin_amdgcn_mfma_f32_16x16x32_f16(a1, Bf, acc1, 0, 0, 0);
        if (kt < 7) { a0 = a0n; a1 = a1n; }
    }

    // ---- epilogue: score[n] = sum_m v[m] * tanh(t[m][n])
    float4v v0 = *reinterpret_cast<const float4v*>(v + h0 + qd * 4);
    float4v v1 = *reinterpret_cast<const float4v*>(v + h0 + 16 + qd * 4);
    float part = 0.f;
    #pragma unroll
    for (int r = 0; r < 4; ++r) {
        part = fmaf(v0[r], fast_tanh(acc0[r]), part);
        part = fmaf(v1[r], fast_tanh(acc1[r]), part);
    }
    part += __shfl_xor(part, 16);   // sum quads (rows m), same n
    part += __shfl_xor(part, 32);
    if (qd == 0) red[mh * 32 + row] = part;
    __syncthreads();
    if (tid < NT) {
        float s = red[tid] + red[32 + tid] + red[64 + tid] + red[96 + tid];
        out[(size_t)b * Nd + n0 + tid] = s;
    }
}

// ---------------------------------------------------------------------------
// softmax over n=2048 per b, in place. (validated round 1)
__global__ void softmax_k(float* __restrict__ out) {
    int b = blockIdx.x;
    float* row = out + (size_t)b * Nd;
    int tid = threadIdx.x;

    float loc[8];
    float mx = -3.4e38f;
    #pragma unroll
    for (int i = 0; i < 8; ++i) {
        loc[i] = row[tid + (i << 8)];
        mx = fmaxf(mx, loc[i]);
    }
    #pragma unroll
    for (int off = 32; off > 0; off >>= 1) mx = fmaxf(mx, __shfl_xor(mx, off));
    __shared__ float s4[4];
    if ((tid & 63) == 0) s4[tid >> 6] = mx;
    __syncthreads();
    mx = fmaxf(fmaxf(s4[0], s4[1]), fmaxf(s4[2], s4[3]));

    float sum = 0.f;
    #pragma unroll
    for (int i = 0; i < 8; ++i) {
        loc[i] = __expf(loc[i] - mx);
        sum += loc[i];
    }
    #pragma unroll
    for (int off = 32; off > 0; off >>= 1) sum += __shfl_xor(sum, off);
    __shared__ float s4b[4];
    if ((tid & 63) == 0) s4b[tid >> 6] = sum;
    __syncthreads();
    sum = s4b[0] + s4b[1] + s4b[2] + s4b[3];

    float inv = 1.0f / sum;
    #pragma unroll
    for (int i = 0; i < 8; ++i) row[tid + (i << 8)] = loc[i] * inv;
}

// ---------------------------------------------------------------------------
extern "C" void kernel_launch(void* const* d_in, const int* in_sizes, int n_in,
                              void* d_out, int out_size, void* d_ws, size_t ws_size,
                              hipStream_t stream) {
    const float* shp = (const float*)d_in[0];   // static_hidden [B,H,N]
    const float* dhp = (const float*)d_in[1];   // dynamic_hidden [B,H,N]
    const float* dec = (const float*)d_in[2];   // decoder_hidden [B,H]
    const float* v   = (const float*)d_in[3];   // [H]
    const float* W   = (const float*)d_in[4];   // [H, 3H]
    float* out = (float*)d_out;                 // [B,1,N]

    _Float16* Wf = (_Float16*)d_ws;             // 32768 halves = 64 KB
    float* cbp = (float*)((char*)d_ws + 65536); // 32768 floats = 128 KB

    hipLaunchKernelGGL(prep_w16, dim3(128), dim3(256), 0, stream, W, Wf);
    hipLaunchKernelGGL(prep_c,   dim3(Bn),  dim3(Hd),  0, stream, W, dec, cbp);
    hipLaunchKernelGGL(score_kernel, dim3(Nd / NT, Bn), dim3(512), 0, stream,
                       shp, dhp, Wf, cbp, v, out);
    hipLaunchKernelGGL(softmax_k, dim3(Bn), dim3(256), 0, stream, out);
}

// Round 5
// 557.551 us; speedup vs baseline: 1.2494x; 1.2494x over previous
//
#include <hip/hip_runtime.h>
#include <cstddef>
#include <cstdint>

#define Bn 256
#define Hd 128
#define Nd 2048
#define K3 384     // W row stride (3H)
#define NT 32      // n-tile of score_kernel
#define BPC 32     // b-values per persistent block (256 / 8 chunks)

typedef _Float16 half8 __attribute__((ext_vector_type(8)));
typedef float    float4v __attribute__((ext_vector_type(4)));
typedef unsigned int u32;

#define ASM_WAIT_VM6()  asm volatile("s_waitcnt vmcnt(6)" ::: "memory")
#define ASM_WAIT_LGKM() asm volatile("s_waitcnt lgkmcnt(0)" ::: "memory")
#define BAR()           __builtin_amdgcn_s_barrier()
#define SFENCE()        __builtin_amdgcn_sched_barrier(0)

__device__ __forceinline__ float fast_tanh(float x) {
    // tanh(x) = 1 - 2/(exp(2x)+1); saturates correctly at +/-inf
    return 1.0f - __fdividef(2.0f, __expf(2.0f * x) + 1.0f);
}

// async global->LDS DMA, 16B per lane. LDS dest wave-uniform base; HW adds lane*16.
__device__ __forceinline__ void dma16(const float* g, const void* l) {
    __builtin_amdgcn_global_load_lds(
        (const __attribute__((address_space(1))) u32*)(uintptr_t)g,
        (__attribute__((address_space(3))) u32*)(u32)(uintptr_t)l,
        16, 0, 0);
}

// ---------------------------------------------------------------------------
// prep 1: Wf[h][k] = fp16(W[h][k]) for k<256  (static+dynamic columns)
__global__ void prep_w16(const float* __restrict__ W, _Float16* __restrict__ Wf) {
    int idx = blockIdx.x * 256 + threadIdx.x;   // 0..32767
    int h = idx >> 8, k = idx & 255;
    Wf[idx] = (_Float16)W[h * K3 + k];
}

// prep 2: c[b][h] = sum_k W[h][256+k] * dec[b][k]  (decoder term, fp32 exact)
__global__ void prep_c(const float* __restrict__ W, const float* __restrict__ dec,
                       float* __restrict__ cb) {
    __shared__ float dl[Hd];
    int b = blockIdx.x;
    int h = threadIdx.x;       // 128 threads
    dl[h] = dec[b * Hd + h];
    __syncthreads();
    float acc = 0.f;
    #pragma unroll 8
    for (int k = 0; k < Hd; ++k)
        acc = fmaf(W[h * K3 + 256 + k], dl[k], acc);
    cb[b * Hd + h] = acc;
}

// ---------------------------------------------------------------------------
// Main: PERSISTENT blocks. grid = 512 blocks (2/CU, LDS 80 KB exact), 512 thr.
// Block -> fixed n-tile (blk&63 -> n0) and b-chunk (blk>>6 -> 32 b's).
// R3 post-mortem: per-block DMA burst + vmcnt(0) drain at barrier = sawtooth
// duty cycle (16 us/block-slot for 1.3 us of memory). Fix: pipeline tiles
// across a persistent loop -- DMA(i+1) issued at top, waited with COUNTED
// s_waitcnt vmcnt(6) (6 newest = DMA(i+1)x4 + cbp(i+1)x2) + raw s_barrier,
// so every load spans a full iteration of compute. W A-fragments persistent
// in registers (loaded once); cbp prefetched one tile ahead.
// R4 fix: no LDS-pointer ARRAY initializer (gfx950 rejects the addrspacecast
// static init) -- buffer selected by wave-uniform ternary at use.
// Per-iter phases (validated R3 algebra): DMA wait -> CVT raw f32 [k][n] ->
// xl f16 [n][k] swizzled (chunk^=(n&7)) -> barrier -> 16 MFMA + tanh/v
// epilogue -> red (aliases xl behind an extra barrier) -> out.
__global__ __launch_bounds__(512, 4)
void score_kernel(const float* __restrict__ shp, const float* __restrict__ dhp,
                  const _Float16* __restrict__ Wf, const float* __restrict__ cbp,
                  const float* __restrict__ v, float* __restrict__ out) {
    __shared__ __align__(16) float    xraw[2][256 * NT];   // 64 KB, [k][n] f32 linear
    __shared__ __align__(16) _Float16 xl[NT * 256];        // 16 KB, [n][k] f16 swizzled
    float* red = reinterpret_cast<float*>(xl);             // alias (guarded by barrier)

    const int tid  = threadIdx.x;
    const int w    = __builtin_amdgcn_readfirstlane(tid >> 6);
    const int lane = tid & 63;
    const int qd   = lane >> 4;
    const int ln   = lane & 15;
    const int blk  = blockIdx.x;
    const int n0   = (blk & 63) * NT;
    const int b0   = (blk >> 6) * BPC;

    const int mh  = w & 3;            // h-tile: h0 = 32*mh
    const int nh  = w >> 2;           // n-half: rows 16*nh..
    const int h0  = mh * 32;
    const int row = nh * 16 + ln;     // 0..31
    const int sw  = row & 7;

    // ---- persistent A fragments + v (Wf is L2-hot; loaded once)
    half8 Af0[8], Af1[8];
    {
        const _Float16* wp0 = Wf + ((h0 + ln) << 8) + qd * 8;
        const _Float16* wp1 = wp0 + (16 << 8);
        #pragma unroll
        for (int kt = 0; kt < 8; ++kt) {
            Af0[kt] = *reinterpret_cast<const half8*>(wp0 + kt * 32);
            Af1[kt] = *reinterpret_cast<const half8*>(wp1 + kt * 32);
        }
    }
    const float4v v0 = *reinterpret_cast<const float4v*>(v + h0 + qd * 4);
    const float4v v1 = *reinterpret_cast<const float4v*>(v + h0 + 16 + qd * 4);

    // ---- DMA addressing (wave w covers logical k rows [32w,32w+32))
    const float* arr = (w < 4) ? shp : dhp;
    const int    kr  = (w & 3) * 32;                 // row within arr
    const size_t bstr = (size_t)Hd * Nd;
    const float* gbase = arr + (size_t)b0 * bstr
                       + (size_t)(kr + (lane >> 3)) * Nd + n0 + 4 * (lane & 7);
    char* const ldst0 = (char*)&xraw[0][0] + (32 * w) * (NT * 4);
    char* const ldst1 = (char*)&xraw[1][0] + (32 * w) * (NT * 4);

    // CVT constants (per thread)
    const int cn  = tid & 31;
    const int cs  = cn & 7;
    const int kc0 = tid >> 5;          // 0..15

    // ---- prologue: stage tile 0, prefetch cbp(0)
    {
        #pragma unroll
        for (int t = 0; t < 4; ++t)
            dma16(gbase + (size_t)(8 * t) * Nd, ldst0 + 8 * t * (NT * 4));
    }
    float4v c0 = *reinterpret_cast<const float4v*>(cbp + (size_t)b0 * Hd + h0 + qd * 4);
    float4v c1 = *reinterpret_cast<const float4v*>(cbp + (size_t)b0 * Hd + h0 + 16 + qd * 4);

    int cur = 0;
    for (int it = 0; it < BPC; ++it) {
        // -- top: issue next tile DMA (wraps harmlessly on last iter) + cbp prefetch
        const int nbi = (it + 1 < BPC) ? it + 1 : 0;
        {
            const float* g = gbase + (size_t)nbi * bstr;
            char* l = cur ? ldst0 : ldst1;
            #pragma unroll
            for (int t = 0; t < 4; ++t)
                dma16(g + (size_t)(8 * t) * Nd, l + 8 * t * (NT * 4));
        }
        float4v c0n = *reinterpret_cast<const float4v*>(cbp + (size_t)(b0 + nbi) * Hd + h0 + qd * 4);
        float4v c1n = *reinterpret_cast<const float4v*>(cbp + (size_t)(b0 + nbi) * Hd + h0 + 16 + qd * 4);

        // -- wait current tile's DMA (all but 6 newest = keep next tile in flight)
        ASM_WAIT_VM6();
        SFENCE();
        BAR();

        // -- CVT: raw[cur] [k][n] f32 -> xl [n][k] f16 swizzled
        {
            const float* rc = cur ? &xraw[1][0] : &xraw[0][0];
            #pragma unroll
            for (int u = 0; u < 2; ++u) {
                const int kc = kc0 + 16 * u;       // 16B k-chunk 0..31
                half8 e;
                #pragma unroll
                for (int j = 0; j < 8; ++j)
                    e[j] = (_Float16)rc[(kc * 8 + j) * NT + cn];
                *reinterpret_cast<half8*>(&xl[cn * 256 + ((kc ^ cs) << 3)]) = e;
            }
        }
        ASM_WAIT_LGKM();
        SFENCE();
        BAR();

        // -- MFMA: A[m=ln][k=qd*8+j]; B[k=qd*8+j][n=ln]
        float4v acc0 = c0, acc1 = c1;
        #pragma unroll
        for (int kt = 0; kt < 8; ++kt) {
            const int ck = kt * 4 + qd;
            half8 Bf = *reinterpret_cast<const half8*>(&xl[row * 256 + ((ck ^ sw) << 3)]);
            acc0 = __builtin_amdgcn_mfma_f32_16x16x32_f16(Af0[kt], Bf, acc0, 0, 0, 0);
            acc1 = __builtin_amdgcn_mfma_f32_16x16x32_f16(Af1[kt], Bf, acc1, 0, 0, 0);
        }

        // -- epilogue: score[n] = sum_m v[m]*tanh(t[m][n])
        float part = 0.f;
        #pragma unroll
        for (int r = 0; r < 4; ++r) {
            part = fmaf(v0[r], fast_tanh(acc0[r]), part);
            part = fmaf(v1[r], fast_tanh(acc1[r]), part);
        }
        part += __shfl_xor(part, 16);
        part += __shfl_xor(part, 32);

        BAR();                       // all xl reads done -> red may alias xl
        SFENCE();
        if (qd == 0) red[mh * 32 + row] = part;
        ASM_WAIT_LGKM();
        SFENCE();
        BAR();
        if (tid < NT) {
            float s = red[tid] + red[32 + tid] + red[64 + tid] + red[96 + tid];
            out[(size_t)(b0 + it) * Nd + n0 + tid] = s;
        }

        cur ^= 1;
        c0 = c0n; c1 = c1n;
    }
}

// ---------------------------------------------------------------------------
// softmax over n=2048 per b, in place. (validated round 1)
__global__ void softmax_k(float* __restrict__ out) {
    int b = blockIdx.x;
    float* row = out + (size_t)b * Nd;
    int tid = threadIdx.x;

    float loc[8];
    float mx = -3.4e38f;
    #pragma unroll
    for (int i = 0; i < 8; ++i) {
        loc[i] = row[tid + (i << 8)];
        mx = fmaxf(mx, loc[i]);
    }
    #pragma unroll
    for (int off = 32; off > 0; off >>= 1) mx = fmaxf(mx, __shfl_xor(mx, off));
    __shared__ float s4[4];
    if ((tid & 63) == 0) s4[tid >> 6] = mx;
    __syncthreads();
    mx = fmaxf(fmaxf(s4[0], s4[1]), fmaxf(s4[2], s4[3]));

    float sum = 0.f;
    #pragma unroll
    for (int i = 0; i < 8; ++i) {
        loc[i] = __expf(loc[i] - mx);
        sum += loc[i];
    }
    #pragma unroll
    for (int off = 32; off > 0; off >>= 1) sum += __shfl_xor(sum, off);
    __shared__ float s4b[4];
    if ((tid & 63) == 0) s4b[tid >> 6] = sum;
    __syncthreads();
    sum = s4b[0] + s4b[1] + s4b[2] + s4b[3];

    float inv = 1.0f / sum;
    #pragma unroll
    for (int i = 0; i < 8; ++i) row[tid + (i << 8)] = loc[i] * inv;
}

// ---------------------------------------------------------------------------
extern "C" void kernel_launch(void* const* d_in, const int* in_sizes, int n_in,
                              void* d_out, int out_size, void* d_ws, size_t ws_size,
                              hipStream_t stream) {
    const float* shp = (const float*)d_in[0];   // static_hidden [B,H,N]
    const float* dhp = (const float*)d_in[1];   // dynamic_hidden [B,H,N]
    const float* dec = (const float*)d_in[2];   // decoder_hidden [B,H]
    const float* v   = (const float*)d_in[3];   // [H]
    const float* W   = (const float*)d_in[4];   // [H, 3H]
    float* out = (float*)d_out;                 // [B,1,N]

    _Float16* Wf = (_Float16*)d_ws;             // 32768 halves = 64 KB
    float* cbp = (float*)((char*)d_ws + 65536); // 32768 floats = 128 KB

    hipLaunchKernelGGL(prep_w16, dim3(128), dim3(256), 0, stream, W, Wf);
    hipLaunchKernelGGL(prep_c,   dim3(Bn),  dim3(Hd),  0, stream, W, dec, cbp);
    hipLaunchKernelGGL(score_kernel, dim3((Nd / NT) * (Bn / BPC)), dim3(512), 0, stream,
                       shp, dhp, Wf, cbp, v, out);
    hipLaunchKernelGGL(softmax_k, dim3(Bn), dim3(256), 0, stream, out);
}